// Round 2
// baseline (10986.766 us; speedup 1.0000x reference)
//
#include <hip/hip_runtime.h>
#include <hip/hip_bf16.h>
#include <cstddef>

#define NN 256      // N
#define PP 256      // P
#define BB 128      // B
#define KK 4        // K
#define NSYS (KK*BB)   // 512

__device__ __forceinline__ float sigmoidf_(float x){ return 1.0f/(1.0f+expf(-x)); }

// ---------------------------------------------------------------------------
// Kernel 1: build Cm (A) and rowsum(Cm) for systems [s0, s0+cs).
// grid = cs*NN blocks (one per (local system, row)), 256 threads (one per col).
// ---------------------------------------------------------------------------
__global__ __launch_bounds__(256) void build_kernel(
    const float* __restrict__ C, const float* __restrict__ rm,
    const float* __restrict__ epsp, const int* __restrict__ bad,
    float* __restrict__ A, float* __restrict__ rowsum, int s0)
{
  const int si = blockIdx.x;
  const int ls = si >> 8;      // local system
  const int i  = si & 255;     // row
  const int s  = s0 + ls;      // global system
  const int k  = s >> 7;       // s / B
  const int b  = s & 127;      // s % B
  const int j  = threadIdx.x;

  const float sk = sigmoidf_(rm[k]);
  const float ek = sigmoidf_(epsp[k]);
  const bool bad_i = bad[b*NN + i] != 0;
  const bool bad_j = bad[b*NN + j] != 0;

  float c  = C[((size_t)b*NN + i)*(NN+PP) + j];
  float x  = sk * c;
  float cf = (1.0f + x) * expf(-x);
  if (i == j) cf += ek;              // diag: C[i][i]==0 -> cf==1, add eps
  float keep = (bad_i == bad_j) ? 1.0f : 0.0f;
  float a = cf * keep;
  A[((size_t)ls*NN + i)*NN + j] = a;

  __shared__ float red[256];
  red[j] = a; __syncthreads();
  #pragma unroll
  for (int off = 128; off > 0; off >>= 1){
    if (j < off) red[j] += red[j + off];
    __syncthreads();
  }
  if (j == 0) rowsum[ls*NN + i] = red[0];
}

// ---------------------------------------------------------------------------
// Kernel 2: in-place LU with partial pivoting per (local) system.
// grid = cs blocks, 256 threads. Thread t owns column t in trailing updates.
// ---------------------------------------------------------------------------
__global__ __launch_bounds__(256) void lu_kernel(
    float* __restrict__ Aall, int* __restrict__ permAll)
{
  __shared__ float red[256];
  __shared__ int   redi[256];
  __shared__ float lcol[256];
  __shared__ int   perm[256];

  const int ls = blockIdx.x;
  float* A = Aall + (size_t)ls*NN*NN;
  const int t = threadIdx.x;

  perm[t] = t;
  __syncthreads();

  for (int kk = 0; kk < NN; ++kk){
    // pivot search: argmax_{i>=kk} |A[i][kk]|
    red[t]  = (t >= kk) ? fabsf(A[t*NN + kk]) : -1.0f;
    redi[t] = t;
    __syncthreads();
    #pragma unroll
    for (int off = 128; off > 0; off >>= 1){
      if (t < off && red[t+off] > red[t]){ red[t] = red[t+off]; redi[t] = redi[t+off]; }
      __syncthreads();
    }
    const int piv = redi[0];
    if (piv != kk){
      float ta = A[kk*NN + t];
      A[kk*NN + t]  = A[piv*NN + t];
      A[piv*NN + t] = ta;
      if (t == 0){ int pp = perm[kk]; perm[kk] = perm[piv]; perm[piv] = pp; }
    }
    __syncthreads();

    const float pv = A[kk*NN + kk];
    const float ur = A[kk*NN + t];
    float m = 0.0f;
    if (t > kk){ m = A[t*NN + kk] / pv; A[t*NN + kk] = m; }
    lcol[t] = m;
    __syncthreads();

    if (t > kk){
      #pragma unroll 4
      for (int i = kk+1; i < NN; ++i){
        A[i*NN + t] -= lcol[i] * ur;
      }
    }
    __syncthreads();
  }
  permAll[ls*NN + t] = perm[t];
}

// ---------------------------------------------------------------------------
// Kernel 3: fused triangular solves + epilogue. 64-wide RHS chunks in LDS.
// grid = cs blocks, 256 threads. RHS built on the fly; out written directly.
// ---------------------------------------------------------------------------
__global__ __launch_bounds__(256) void solve_epi_kernel(
    const float* __restrict__ Aall, const int* __restrict__ permAll,
    const float* __restrict__ rowsum,
    const float* __restrict__ C, const float* __restrict__ val,
    const int* __restrict__ bad, const float* __restrict__ rm,
    float* __restrict__ out, int s0)
{
  __shared__ float tile[NN*64];   // 64 KiB
  const int ls = blockIdx.x;
  const int s  = s0 + ls;
  const int k  = s >> 7;
  const int b  = s & 127;
  const float* A    = Aall + (size_t)ls*NN*NN;
  const int*   perm = permAll + ls*NN;
  const float* rs   = rowsum + ls*NN;
  const int t = threadIdx.x;
  const float sk = sigmoidf_(rm[k]);

  for (int c0 = 0; c0 < PP; c0 += 64){
    // build permuted RHS chunk on the fly: tile[i][c] = b[perm[i]][c0+c]
    for (int e = t; e < NN*64; e += 256){
      int i = e >> 6, c = e & 63;
      int pi = perm[i];
      float cb = C[((size_t)b*NN + pi)*(NN+PP) + NN + c0 + c];
      float xb = sk * cb;
      float bf = (1.0f + xb) * expf(-xb);
      if (bad[b*NN + pi]) bf = 0.0f;
      tile[e] = bf;
    }
    __syncthreads();

    // forward substitution (unit lower)
    for (int kk = 0; kk < NN-1; ++kk){
      const int nrem = (NN-1-kk)*64;
      const float pr = tile[kk*64 + (t & 63)];
      for (int e = t; e < nrem; e += 256){
        int i = kk + 1 + (e >> 6);
        int c = e & 63;
        tile[i*64 + c] -= A[i*NN + kk] * pr;
      }
      __syncthreads();
    }

    // backward substitution
    for (int kk = NN-1; kk >= 0; --kk){
      const float ukk = A[kk*NN + kk];
      if (t < 64) tile[kk*64 + t] /= ukk;
      __syncthreads();
      const float pr = tile[kk*64 + (t & 63)];
      for (int e = t; e < kk*64; e += 256){
        int i = e >> 6, c = e & 63;
        tile[i*64 + c] -= A[i*NN + kk] * pr;
      }
      __syncthreads();
    }

    // epilogue: column reductions + blend + output (threads 0..63, one per col)
    if (t < 64){
      const int p = c0 + t;
      float sdv = 0.0f, sabs = 0.0f, s1v = 0.0f, s1 = 0.0f;
      for (int j = 0; j < NN; ++j){
        float d = tile[j*64 + t];
        float v = val[(b*NN + j)*KK + k];
        if (v != v) v = 0.0f;
        float cb = C[((size_t)b*NN + j)*(NN+PP) + NN + p];
        float xb = sk * cb;
        float bo = (1.0f + xb) * expf(-xb);
        if (bad[b*NN + j]) bo = 0.0f;
        float d1 = bo / rs[j];
        sdv  += d * v;
        sabs += fabsf(d);
        s1v  += d1 * v;
        s1   += d1;
      }
      float wg    = fminf(fmaxf((sabs - 1.0f)*2.0f, 0.0f), 1.0f);
      float denom = fmaxf(s1, 1.0f);
      out[((size_t)b*PP + p)*KK + k] = (1.0f - wg)*sdv + (wg/denom)*s1v;
    }
    __syncthreads();
  }
}

// ---------------------------------------------------------------------------
extern "C" void kernel_launch(void* const* d_in, const int* in_sizes, int n_in,
                              void* d_out, int out_size, void* d_ws, size_t ws_size,
                              hipStream_t stream)
{
  const float* C    = (const float*)d_in[0];
  const float* val  = (const float*)d_in[1];
  const float* rm   = (const float*)d_in[2];
  const float* epsp = (const float*)d_in[3];
  const int*   bad  = (const int*)d_in[4];
  float* out = (float*)d_out;

  // per-system workspace: A (NN*NN f32) + rowsum (NN f32) + perm (NN i32)
  const size_t per_sys = (size_t)NN*NN*4 + (size_t)NN*4 + (size_t)NN*4;
  int chunk = (int)(ws_size / per_sys);
  if (chunk < 1)    chunk = 1;
  if (chunk > NSYS) chunk = NSYS;

  float* ws     = (float*)d_ws;
  float* A      = ws;
  float* rowsum = A + (size_t)chunk*NN*NN;
  int*   perm   = (int*)(rowsum + (size_t)chunk*NN);

  for (int s0 = 0; s0 < NSYS; s0 += chunk){
    int cs = (NSYS - s0 < chunk) ? (NSYS - s0) : chunk;
    build_kernel<<<cs*NN, 256, 0, stream>>>(C, rm, epsp, bad, A, rowsum, s0);
    lu_kernel<<<cs, 256, 0, stream>>>(A, perm);
    solve_epi_kernel<<<cs, 256, 0, stream>>>(A, perm, rowsum, C, val, bad, rm, out, s0);
  }
}

// Round 3
// 2029.244 us; speedup vs baseline: 5.4142x; 5.4142x over previous
//
#include <hip/hip_runtime.h>
#include <hip/hip_bf16.h>
#include <cstddef>

#define NN 256      // N
#define PP 256      // P
#define BB 128      // B
#define KK 4        // K
#define NSYS (KK*BB)   // 512
#define PW 16       // panel / block width
#define NPAN (NN/PW)

__device__ __forceinline__ float sigmoidf_(float x){ return 1.0f/(1.0f+expf(-x)); }

// ---------------------------------------------------------------------------
// Kernel 1: build Cm (A) and rowsum(Cm) for systems [s0, s0+cs).
// ---------------------------------------------------------------------------
__global__ __launch_bounds__(256) void build_kernel(
    const float* __restrict__ C, const float* __restrict__ rm,
    const float* __restrict__ epsp, const int* __restrict__ bad,
    float* __restrict__ A, float* __restrict__ rowsum, int s0)
{
  const int si = blockIdx.x;
  const int ls = si >> 8;
  const int i  = si & 255;
  const int s  = s0 + ls;
  const int k  = s >> 7;
  const int b  = s & 127;
  const int j  = threadIdx.x;

  const float sk = sigmoidf_(rm[k]);
  const float ek = sigmoidf_(epsp[k]);
  const bool bad_i = bad[b*NN + i] != 0;
  const bool bad_j = bad[b*NN + j] != 0;

  float c  = C[((size_t)b*NN + i)*(NN+PP) + j];
  float x  = sk * c;
  float cf = (1.0f + x) * expf(-x);
  if (i == j) cf += ek;
  float keep = (bad_i == bad_j) ? 1.0f : 0.0f;
  float a = cf * keep;
  A[((size_t)ls*NN + i)*NN + j] = a;

  __shared__ float red[256];
  red[j] = a; __syncthreads();
  #pragma unroll
  for (int off = 128; off > 0; off >>= 1){
    if (j < off) red[j] += red[j + off];
    __syncthreads();
  }
  if (j == 0) rowsum[ls*NN + i] = red[0];
}

// ---------------------------------------------------------------------------
// Kernel 2: blocked LU with partial pivoting, panel width 16.
// One block (256 threads) per system. Panel in LDS; trailing update = rank-16.
// ---------------------------------------------------------------------------
__global__ __launch_bounds__(256) void lu_kernel(
    float* __restrict__ Aall, int* __restrict__ permAll)
{
  __shared__ float panel[NN][PW+1];   // 17 KiB, padded (column access conflict-free)
  __shared__ float urow[PW][NN];      // 16 KiB U12 staging
  __shared__ float redv[4];
  __shared__ int   redi[4];
  __shared__ int   pivrow[PW];
  __shared__ int   perm[NN];

  const int ls = blockIdx.x;
  float* __restrict__ A = Aall + (size_t)ls*NN*NN;
  const int t = threadIdx.x;
  const int lane = t & 63, wid = t >> 6;

  perm[t] = t;
  __syncthreads();

  for (int I = 0; I < NPAN; ++I){
    const int col0 = I*PW;
    const int M = NN - col0;          // active panel rows

    // ---- load panel rows col0..255, cols col0..col0+15 (float4 reads) ----
    for (int e = t; e < M*4; e += 256){
      int r = e >> 2, q = e & 3;
      float4 v4 = *(const float4*)(A + (size_t)(col0+r)*NN + col0 + q*4);
      panel[r][q*4+0] = v4.x; panel[r][q*4+1] = v4.y;
      panel[r][q*4+2] = v4.z; panel[r][q*4+3] = v4.w;
    }
    __syncthreads();

    // ---- factor panel (16 columns, pivoted) ----
    for (int c = 0; c < PW; ++c){
      // argmax |panel[r][c]| over r in [c, M); thread t <-> row t
      float v = -1.0f; int vi = t;
      if (t >= c && t < M) v = fabsf(panel[t][c]);
      #pragma unroll
      for (int off = 32; off > 0; off >>= 1){
        float ov = __shfl_down(v, off);
        int   oi = __shfl_down(vi, off);
        if (ov > v){ v = ov; vi = oi; }
      }
      if (lane == 0){ redv[wid] = v; redi[wid] = vi; }
      __syncthreads();
      if (t == 0){
        float bv = redv[0]; int bi = redi[0];
        #pragma unroll
        for (int w = 1; w < 4; ++w) if (redv[w] > bv){ bv = redv[w]; bi = redi[w]; }
        pivrow[c] = bi;
        int tmp = perm[col0+c]; perm[col0+c] = perm[col0+bi]; perm[col0+bi] = tmp;
      }
      __syncthreads();
      const int pr = pivrow[c];
      if (pr != c){
        if (t < PW){
          float tmp = panel[c][t]; panel[c][t] = panel[pr][t]; panel[pr][t] = tmp;
        }
        __syncthreads();
      }
      const float pv = panel[c][c];
      if (t > c && t < M){
        float m = panel[t][c] / pv;
        panel[t][c] = m;
        #pragma unroll
        for (int j = c+1; j < PW; ++j)
          panel[t][j] -= m * panel[c][j];
      }
      __syncthreads();
    }

    // ---- apply the 16 row swaps to global A outside panel columns ----
    for (int c = 0; c < PW; ++c){
      const int pr = pivrow[c];
      if (pr != c){
        const size_t ra = (size_t)(col0 + c)*NN, rb = (size_t)(col0 + pr)*NN;
        const int j = t;   // 256 threads cover all 256 columns
        if (!(j >= col0 && j < col0+PW)){
          float tmp = A[ra + j]; A[ra + j] = A[rb + j]; A[rb + j] = tmp;
        }
        __syncthreads();
      }
    }

    // ---- write factored panel back ----
    for (int e = t; e < M*PW; e += 256){
      int r = e >> 4, c = e & 15;
      A[(size_t)(col0+r)*NN + col0 + c] = panel[r][c];
    }

    const int W = M - PW;             // trailing dimension
    if (W > 0){
      // ---- U12 = L11^{-1} A12 : one thread per column, in-register solve ----
      if (t < W){
        const int j = col0 + PW + t;
        float u[PW];
        #pragma unroll
        for (int c = 0; c < PW; ++c) u[c] = A[(size_t)(col0+c)*NN + j];
        #pragma unroll
        for (int c = 0; c < PW; ++c){
          float sv = u[c];
          #pragma unroll
          for (int kk = 0; kk < c; ++kk) sv -= panel[c][kk] * u[kk];
          u[c] = sv;
          urow[c][t] = sv;
          A[(size_t)(col0+c)*NN + j] = sv;
        }
      }
      __syncthreads();

      // ---- trailing update A22 -= L21 * U12, 2-row register blocking ----
      for (int r2 = wid*2; r2 < W; r2 += 8){
        const int r2b = r2 + 1;
        const bool two = (r2b < W);
        float La[PW], Lb[PW];
        #pragma unroll
        for (int c = 0; c < PW; ++c){
          La[c] = panel[PW + r2][c];
          Lb[c] = two ? panel[PW + r2b][c] : 0.0f;
        }
        float* Ar0 = A + (size_t)(col0+PW+r2)*NN + col0+PW;
        float* Ar1 = A + (size_t)(col0+PW+(two?r2b:r2))*NN + col0+PW;
        for (int j2 = lane; j2 < W; j2 += 64){
          float a0 = Ar0[j2];
          float a1 = Ar1[j2];
          #pragma unroll
          for (int c = 0; c < PW; ++c){
            float uu = urow[c][j2];
            a0 -= La[c]*uu;
            a1 -= Lb[c]*uu;
          }
          Ar0[j2] = a0;
          if (two) Ar1[j2] = a1;
        }
      }
      __syncthreads();
    }
  }
  permAll[ls*NN + t] = perm[t];
}

// ---------------------------------------------------------------------------
// Kernel 3: blocked triangular solves + epilogue. 64-wide RHS chunks in LDS.
// ---------------------------------------------------------------------------
__global__ __launch_bounds__(256) void solve_epi_kernel(
    const float* __restrict__ Aall, const int* __restrict__ permAll,
    const float* __restrict__ rowsum,
    const float* __restrict__ C, const float* __restrict__ val,
    const int* __restrict__ bad, const float* __restrict__ rm,
    float* __restrict__ out, int s0)
{
  __shared__ float tile[NN][64];      // 64 KiB
  __shared__ float dblk[PW][PW+1];    // staged diagonal block
  __shared__ float ep[4][4][64];      // epilogue partials

  const int ls = blockIdx.x;
  const int s  = s0 + ls;
  const int k  = s >> 7, b = s & 127;
  const float* __restrict__ A = Aall + (size_t)ls*NN*NN;
  const int* perm = permAll + ls*NN;
  const float* rs = rowsum + ls*NN;
  const int t = threadIdx.x;
  const int lane = t & 63, wid = t >> 6;
  const float sk = sigmoidf_(rm[k]);

  for (int c0 = 0; c0 < PP; c0 += 64){
    // ---- build permuted RHS chunk on the fly ----
    for (int e = t; e < NN*64; e += 256){
      int i = e >> 6, c = e & 63;
      int pi = perm[i];
      float cb = C[((size_t)b*NN + pi)*(NN+PP) + NN + c0 + c];
      float xb = sk * cb;
      float bf = (1.0f + xb) * expf(-xb);
      if (bad[b*NN + pi]) bf = 0.0f;
      tile[i][c] = bf;
    }
    __syncthreads();

    // ---- forward substitution, blocked by 16 ----
    for (int J = 0; J < NPAN; ++J){
      const int j0 = J*PW;
      if (t < PW*PW) dblk[t>>4][t&15] = A[(size_t)(j0 + (t>>4))*NN + j0 + (t&15)];
      __syncthreads();
      if (wid == 0){                      // wave-synchronous diag solve
        float x[PW];
        #pragma unroll
        for (int jj = 0; jj < PW; ++jj){
          float sv = tile[j0+jj][lane];
          #pragma unroll
          for (int kk = 0; kk < jj; ++kk) sv -= dblk[jj][kk] * x[kk];
          x[jj] = sv;
          tile[j0+jj][lane] = sv;
        }
      }
      __syncthreads();
      if (j0 + PW < NN){                  // rank-16 update of rows below
        float x[PW];
        #pragma unroll
        for (int jj = 0; jj < PW; ++jj) x[jj] = tile[j0+jj][lane];
        for (int i = j0 + PW + wid; i < NN; i += 4){
          const float4* Ar4 = (const float4*)(A + (size_t)i*NN + j0);
          float4 a0 = Ar4[0], a1 = Ar4[1], a2 = Ar4[2], a3 = Ar4[3];
          float acc = tile[i][lane];
          acc -= a0.x*x[0]  + a0.y*x[1]  + a0.z*x[2]  + a0.w*x[3];
          acc -= a1.x*x[4]  + a1.y*x[5]  + a1.z*x[6]  + a1.w*x[7];
          acc -= a2.x*x[8]  + a2.y*x[9]  + a2.z*x[10] + a2.w*x[11];
          acc -= a3.x*x[12] + a3.y*x[13] + a3.z*x[14] + a3.w*x[15];
          tile[i][lane] = acc;
        }
      }
      __syncthreads();
    }

    // ---- backward substitution, blocked by 16 ----
    for (int J = NPAN-1; J >= 0; --J){
      const int j0 = J*PW;
      if (t < PW*PW) dblk[t>>4][t&15] = A[(size_t)(j0 + (t>>4))*NN + j0 + (t&15)];
      __syncthreads();
      if (wid == 0){
        float x[PW];
        #pragma unroll
        for (int jj = PW-1; jj >= 0; --jj){
          float sv = tile[j0+jj][lane];
          #pragma unroll
          for (int kk = jj+1; kk < PW; ++kk) sv -= dblk[jj][kk] * x[kk];
          sv /= dblk[jj][jj];
          x[jj] = sv;
          tile[j0+jj][lane] = sv;
        }
      }
      __syncthreads();
      if (j0 > 0){                        // rank-16 update of rows above
        float x[PW];
        #pragma unroll
        for (int jj = 0; jj < PW; ++jj) x[jj] = tile[j0+jj][lane];
        for (int i = wid; i < j0; i += 4){
          const float4* Ar4 = (const float4*)(A + (size_t)i*NN + j0);
          float4 a0 = Ar4[0], a1 = Ar4[1], a2 = Ar4[2], a3 = Ar4[3];
          float acc = tile[i][lane];
          acc -= a0.x*x[0]  + a0.y*x[1]  + a0.z*x[2]  + a0.w*x[3];
          acc -= a1.x*x[4]  + a1.y*x[5]  + a1.z*x[6]  + a1.w*x[7];
          acc -= a2.x*x[8]  + a2.y*x[9]  + a2.z*x[10] + a2.w*x[11];
          acc -= a3.x*x[12] + a3.y*x[13] + a3.z*x[14] + a3.w*x[15];
          tile[i][lane] = acc;
        }
      }
      __syncthreads();
    }

    // ---- epilogue: 4-wave partial column reductions + combine ----
    {
      const int p = c0 + lane;
      float sdv=0.f, sabs=0.f, s1v=0.f, s1=0.f;
      for (int j = wid*64; j < wid*64 + 64; ++j){
        float d = tile[j][lane];
        float v = val[(b*NN + j)*KK + k];
        if (v != v) v = 0.0f;
        float cb = C[((size_t)b*NN + j)*(NN+PP) + NN + p];
        float xb = sk*cb;
        float bo = (1.0f+xb)*expf(-xb);
        if (bad[b*NN + j]) bo = 0.0f;
        float d1 = bo / rs[j];
        sdv += d*v; sabs += fabsf(d); s1v += d1*v; s1 += d1;
      }
      ep[0][wid][lane]=sdv; ep[1][wid][lane]=sabs; ep[2][wid][lane]=s1v; ep[3][wid][lane]=s1;
    }
    __syncthreads();
    if (wid == 0){
      float sdv = ep[0][0][lane]+ep[0][1][lane]+ep[0][2][lane]+ep[0][3][lane];
      float sabs= ep[1][0][lane]+ep[1][1][lane]+ep[1][2][lane]+ep[1][3][lane];
      float s1v = ep[2][0][lane]+ep[2][1][lane]+ep[2][2][lane]+ep[2][3][lane];
      float s1  = ep[3][0][lane]+ep[3][1][lane]+ep[3][2][lane]+ep[3][3][lane];
      float wg    = fminf(fmaxf((sabs - 1.0f)*2.0f, 0.0f), 1.0f);
      float denom = fmaxf(s1, 1.0f);
      out[((size_t)b*PP + c0 + lane)*KK + k] = (1.0f - wg)*sdv + (wg/denom)*s1v;
    }
    __syncthreads();
  }
}

// ---------------------------------------------------------------------------
extern "C" void kernel_launch(void* const* d_in, const int* in_sizes, int n_in,
                              void* d_out, int out_size, void* d_ws, size_t ws_size,
                              hipStream_t stream)
{
  const float* C    = (const float*)d_in[0];
  const float* val  = (const float*)d_in[1];
  const float* rm   = (const float*)d_in[2];
  const float* epsp = (const float*)d_in[3];
  const int*   bad  = (const int*)d_in[4];
  float* out = (float*)d_out;

  const size_t per_sys = (size_t)NN*NN*4 + (size_t)NN*4 + (size_t)NN*4;
  int chunk = (int)(ws_size / per_sys);
  if (chunk < 1)    chunk = 1;
  if (chunk > NSYS) chunk = NSYS;

  float* ws     = (float*)d_ws;
  float* A      = ws;
  float* rowsum = A + (size_t)chunk*NN*NN;
  int*   perm   = (int*)(rowsum + (size_t)chunk*NN);

  for (int s0 = 0; s0 < NSYS; s0 += chunk){
    int cs = (NSYS - s0 < chunk) ? (NSYS - s0) : chunk;
    build_kernel<<<cs*NN, 256, 0, stream>>>(C, rm, epsp, bad, A, rowsum, s0);
    lu_kernel<<<cs, 256, 0, stream>>>(A, perm);
    solve_epi_kernel<<<cs, 256, 0, stream>>>(A, perm, rowsum, C, val, bad, rm, out, s0);
  }
}